// Round 4
// baseline (2623.288 us; speedup 1.0000x reference)
//
#include <hip/hip_runtime.h>
#include <math.h>
#include <float.h>

#define D        64
#define NE       8192
#define NROWS    32768
#define NELEM    (NROWS * D)
#define BETA     0.25f
#define MARGIN   0.75f

#define NTILE    (NE / 16)            // 512 code tiles of 16 codes
#define TPC      16                   // tiles per LDS chunk
#define NCHUNK   (NTILE / TPC)        // 32 chunks
#define CHUNK_US (TPC * 1024)         // ushorts per chunk (16 tiles * 2 KiB)

typedef __attribute__((ext_vector_type(8))) short bf16x8;
typedef __attribute__((ext_vector_type(4))) float f32x4;
typedef __attribute__((ext_vector_type(4))) unsigned int u32x4;

__device__ __forceinline__ unsigned short f2bf(float f) {
    unsigned u = __builtin_bit_cast(unsigned, f);
    unsigned r = (u + 0x7FFFu + ((u >> 16) & 1u)) >> 16;   // round-nearest-even
    return (unsigned short)r;
}

// ---------------- ws layout (bytes) ----------------
// 0       : wn      (8192 f32, exact fp32 ||w||^2)
// 32768   : counts  (8192 f32)
// 65536   : sumsq   (1 double)
// 66048   : idxbuf  (32768 int)
// 197120  : flags   (32768 int)
// 393216  : Wpk     (packed bf16 of -2W, 1 MiB)

// Kernel A: wn, packed bf16 codebook (-2W), zero accumulators.
// Wpk frag layout: tile t (16 codes), K-half h:
//   ushort index (t*2 + h)*512 + (g*16 + cl)*8 + j
// so lane l of a wave reads its 16x16x32 B-fragment (col=l&15, k=(l>>4)*8+j)
// as one contiguous 16 B ds_read_b128 at lane*16 bytes.
__global__ void prep_kernel(const float* __restrict__ W,
                            float* __restrict__ wn,
                            unsigned short* __restrict__ Wpk,
                            float* __restrict__ counts,
                            double* __restrict__ sumsq)
{
    int k = blockIdx.x * 256 + threadIdx.x;  // 0..8191
    const float4* wp = (const float4*)(W + (size_t)k * D);
    float w[64]; float s = 0.f;
#pragma unroll
    for (int j = 0; j < 16; ++j) {
        float4 v = wp[j];
        w[4*j+0]=v.x; w[4*j+1]=v.y; w[4*j+2]=v.z; w[4*j+3]=v.w;
        s += v.x*v.x + v.y*v.y + v.z*v.z + v.w*v.w;
    }
    wn[k] = s;
    counts[k] = 0.f;
    if (k == 0) *sumsq = 0.0;

    unsigned short hb[64];
#pragma unroll
    for (int d = 0; d < 64; ++d) hb[d] = f2bf(-2.0f * w[d]);

    const int t = k >> 4, cl = k & 15;
#pragma unroll
    for (int h = 0; h < 2; ++h)
#pragma unroll
    for (int g = 0; g < 4; ++g) {
        const unsigned short* src = hb + h*32 + g*8;
        u32x4 pk;
#pragma unroll
        for (int j = 0; j < 4; ++j)
            pk[j] = (unsigned)src[2*j] | ((unsigned)src[2*j+1] << 16);
        *(u32x4*)(Wpk + (size_t)(((t*2 + h)*512) + (g*16 + cl)*8)) = pk;
    }
}

// Kernel B: MFMA argmin, single bf16 hi-pass.
// Block = 4 waves; wave owns a 16-row strip and sweeps all 8192 codes.
// score = wn[c] + zh*(-2W)h via mfma_f32_16x16x32_bf16 (C-init = wn;
// all 4 C-regs of a lane share one code column [m89]).
// Tracks (best, besti, best2); rows with best2-best < MARGIN get exact rescue.
__global__ __launch_bounds__(256, 2) void vq_mfma_kernel(
    const float* __restrict__ z,
    const unsigned short* __restrict__ Wpk,
    const float* __restrict__ wn,
    int* __restrict__ idxbuf,
    int* __restrict__ flags)
{
    __shared__ __align__(16) unsigned short lds[2 * CHUNK_US];  // 64 KiB dbuf

    const int tid  = threadIdx.x;
    const int lane = tid & 63;
    const int wv   = tid >> 6;
    const int strip   = blockIdx.x * 4 + wv;       // 0..2047
    const int rowbase = strip * 16;
    const int cl = lane & 15;                      // A row / D col within tile
    const int kg = lane >> 4;                      // k-group

    // A-fragments (z hi) for K-halves h=0,1; lane: row=cl, k=kg*8+j
    bf16x8 a_h[2];
#pragma unroll
    for (int h = 0; h < 2; ++h) {
        const float* zp = z + (size_t)(rowbase + cl) * D + h*32 + kg*8;
        float4 f0 = ((const float4*)zp)[0];
        float4 f1 = ((const float4*)zp)[1];
        float f[8] = {f0.x,f0.y,f0.z,f0.w,f1.x,f1.y,f1.z,f1.w};
        bf16x8 hh;
#pragma unroll
        for (int j = 0; j < 8; ++j) hh[j] = (short)f2bf(f[j]);
        a_h[h] = hh;
    }

    float best[4]  = {FLT_MAX, FLT_MAX, FLT_MAX, FLT_MAX};
    float best2[4] = {FLT_MAX, FLT_MAX, FLT_MAX, FLT_MAX};
    int   besti[4] = {0,0,0,0};

    const u32x4* gsrc = (const u32x4*)Wpk;   // 2048 u32x4 per 32 KiB chunk
    u32x4 stg[8];

    // prologue: stage chunk 0
#pragma unroll
    for (int i = 0; i < 8; ++i) stg[i] = gsrc[i*256 + tid];
    {
        u32x4* ld = (u32x4*)lds;
#pragma unroll
        for (int i = 0; i < 8; ++i) ld[i*256 + tid] = stg[i];
    }
    __syncthreads();

    int buf = 0;
    for (int c = 0; c < NCHUNK; ++c) {
        if (c + 1 < NCHUNK) {
            const u32x4* gs = gsrc + (size_t)(c+1) * 2048;
#pragma unroll
            for (int i = 0; i < 8; ++i) stg[i] = gs[i*256 + tid];
        }

        float wnv[TPC];
#pragma unroll
        for (int tt = 0; tt < TPC; ++tt)
            wnv[tt] = wn[(c*TPC + tt)*16 + cl];

        const unsigned short* lb = lds + buf * CHUNK_US;
#pragma unroll
        for (int p = 0; p < 8; ++p) {
            const int lt0 = 2*p, lt1 = 2*p + 1;
            const unsigned short* b0p = lb + lt0*1024;
            const unsigned short* b1p = lb + lt1*1024;
            bf16x8 b0h0 = *(const bf16x8*)(b0p +   0 + lane*8);
            bf16x8 b0h1 = *(const bf16x8*)(b0p + 512 + lane*8);
            bf16x8 b1h0 = *(const bf16x8*)(b1p +   0 + lane*8);
            bf16x8 b1h1 = *(const bf16x8*)(b1p + 512 + lane*8);

            f32x4 acc0 = {wnv[lt0], wnv[lt0], wnv[lt0], wnv[lt0]};
            f32x4 acc1 = {wnv[lt1], wnv[lt1], wnv[lt1], wnv[lt1]};
            acc0 = __builtin_amdgcn_mfma_f32_16x16x32_bf16(a_h[0], b0h0, acc0, 0,0,0);
            acc1 = __builtin_amdgcn_mfma_f32_16x16x32_bf16(a_h[0], b1h0, acc1, 0,0,0);
            acc0 = __builtin_amdgcn_mfma_f32_16x16x32_bf16(a_h[1], b0h1, acc0, 0,0,0);
            acc1 = __builtin_amdgcn_mfma_f32_16x16x32_bf16(a_h[1], b1h1, acc1, 0,0,0);

            const int code0 = (c*TPC + lt0)*16 + cl;
            const int code1 = (c*TPC + lt1)*16 + cl;
#pragma unroll
            for (int q = 0; q < 4; ++q) {
                float s0 = acc0[q];
                best2[q] = fminf(best2[q], fmaxf(best[q], s0));
                besti[q] = (s0 < best[q]) ? code0 : besti[q];
                best[q]  = fminf(best[q], s0);
                float s1 = acc1[q];
                best2[q] = fminf(best2[q], fmaxf(best[q], s1));
                besti[q] = (s1 < best[q]) ? code1 : besti[q];
                best[q]  = fminf(best[q], s1);
            }
        }
        __syncthreads();
        if (c + 1 < NCHUNK) {
            u32x4* ld = (u32x4*)(lds + (buf ^ 1) * CHUNK_US);
#pragma unroll
            for (int i = 0; i < 8; ++i) ld[i*256 + tid] = stg[i];
        }
        __syncthreads();
        buf ^= 1;
    }

    // cross-lane reduce over the 16 code-columns (lanes sharing lane>>4)
#pragma unroll
    for (int m = 1; m < 16; m <<= 1) {
#pragma unroll
        for (int q = 0; q < 4; ++q) {
            float ob1 = __shfl_xor(best[q],  m, 64);
            int   oi  = __shfl_xor(besti[q], m, 64);
            float ob2 = __shfl_xor(best2[q], m, 64);
            float nb2 = fminf(fminf(best2[q], ob2), fmaxf(best[q], ob1));
            if (ob1 < best[q]) { best[q] = ob1; besti[q] = oi; }
            best2[q] = nb2;
        }
    }
    if (cl == 0) {
#pragma unroll
        for (int q = 0; q < 4; ++q) {
            int row = rowbase + kg*4 + q;     // C/D: row=(lane>>4)*4+reg [m89]
            idxbuf[row] = besti[q];
            flags[row]  = (best2[q] - best[q] < MARGIN) ? 1 : 0;
        }
    }
}

// Kernel C: exact fp32 rescue for flagged (near-tie) rows.
__global__ void rescue_kernel(const float* __restrict__ z,
                              const float* __restrict__ W,
                              const float* __restrict__ wn,
                              const int* __restrict__ flags,
                              int* __restrict__ idxbuf)
{
    __shared__ __align__(16) float zr[64];
    __shared__ float rv[256];
    __shared__ int   ri[256];
    const int tid = threadIdx.x;
    for (int row = blockIdx.x; row < NROWS; row += gridDim.x) {
        if (!flags[row]) continue;            // block-uniform branch
        __syncthreads();
        if (tid < 16) ((float4*)zr)[tid] = ((const float4*)(z + (size_t)row * D))[tid];
        __syncthreads();
        float best = FLT_MAX; int bi = 0;
        for (int cc = tid; cc < NE; cc += 256) {
            const float4* wp = (const float4*)(W + (size_t)cc * D);
            float a0=0,a1=0,a2=0,a3=0;
#pragma unroll
            for (int j = 0; j < 16; ++j) {
                float4 wv2 = wp[j];
                a0 += zr[4*j+0]*wv2.x; a1 += zr[4*j+1]*wv2.y;
                a2 += zr[4*j+2]*wv2.z; a3 += zr[4*j+3]*wv2.w;
            }
            float s = wn[cc] - 2.0f*((a0+a1)+(a2+a3));
            if (s < best) { best = s; bi = cc; }   // strict < => first index wins
        }
        rv[tid] = best; ri[tid] = bi;
        __syncthreads();
        for (int off = 128; off > 0; off >>= 1) {
            if (tid < off) {
                float v2 = rv[tid+off]; int i2 = ri[tid+off];
                if (v2 < rv[tid] || (v2 == rv[tid] && i2 < ri[tid])) { rv[tid]=v2; ri[tid]=i2; }
            }
            __syncthreads();
        }
        if (tid == 0) idxbuf[row] = ri[0];
        __syncthreads();
    }
}

// Kernel D: gather z_q, out_idx, counts, sumsq
__global__ void finalize_kernel(const float* __restrict__ z,
                                const float* __restrict__ W,
                                const int* __restrict__ idxbuf,
                                float* __restrict__ out_zq,
                                float* __restrict__ out_idx,
                                float* __restrict__ counts,
                                double* __restrict__ sumsq)
{
    const int n = blockIdx.x * 256 + threadIdx.x;  // 0..32767
    const int bi = idxbuf[n];
    out_idx[n] = (float)bi;
    atomicAdd(&counts[bi], 1.0f);

    const float4* wp = (const float4*)(W + (size_t)bi * D);
    const float4* zp = (const float4*)(z + (size_t)n  * D);
    float4*       op = (float4*)(out_zq + (size_t)n * D);
    float ss = 0.f;
#pragma unroll
    for (int j = 0; j < 16; ++j) {
        float4 wv = wp[j];
        float4 zv = zp[j];
        float dx = wv.x - zv.x, dy = wv.y - zv.y, dz = wv.z - zv.z, dw = wv.w - zv.w;
        ss += dx*dx + dy*dy + dz*dz + dw*dw;
        op[j] = wv;
    }
    __shared__ float red[256];
    red[threadIdx.x] = ss;
    __syncthreads();
#pragma unroll
    for (int off = 128; off > 0; off >>= 1) {
        if (threadIdx.x < off) red[threadIdx.x] += red[threadIdx.x + off];
        __syncthreads();
    }
    if (threadIdx.x == 0) atomicAdd(sumsq, (double)red[0]);
}

// Kernel E: scalars (loss, perplexity)
__global__ void scalars_kernel(const float* __restrict__ counts,
                               const double* __restrict__ sumsq,
                               float* __restrict__ out_loss,
                               float* __restrict__ out_ppl)
{
    __shared__ float red[256];
    float acc = 0.f;
    for (int k = threadIdx.x; k < NE; k += 256) {
        float p = counts[k] * (1.0f / (float)NROWS);
        acc += p * logf(p + 1e-12f);
    }
    red[threadIdx.x] = acc;
    __syncthreads();
#pragma unroll
    for (int off = 128; off > 0; off >>= 1) {
        if (threadIdx.x < off) red[threadIdx.x] += red[threadIdx.x + off];
        __syncthreads();
    }
    if (threadIdx.x == 0) {
        out_ppl[0]  = expf(-red[0]);
        out_loss[0] = (float)(sumsq[0] * ((1.0 + (double)BETA) / (double)NELEM));
    }
}

extern "C" void kernel_launch(void* const* d_in, const int* in_sizes, int n_in,
                              void* d_out, int out_size, void* d_ws, size_t ws_size,
                              hipStream_t stream) {
    const float* z = (const float*)d_in[0];   // [32,1024,64] fp32
    const float* W = (const float*)d_in[1];   // [8192,64]    fp32

    float* out      = (float*)d_out;
    float* out_zq   = out;                     // 2097152
    float* out_loss = out + NELEM;             // 1
    float* out_idx  = out + NELEM + 1;         // 32768 (as float)
    float* out_ppl  = out + NELEM + 1 + NROWS; // 1

    char* wsb = (char*)d_ws;
    float*          wn     = (float*)wsb;                 // 8192 f32
    float*          counts = (float*)(wsb + 32768);       // 8192 f32
    double*         sumsq  = (double*)(wsb + 65536);      // 1 f64
    int*            idxbuf = (int*)(wsb + 66048);         // 32768 int
    int*            flags  = (int*)(wsb + 197120);        // 32768 int
    unsigned short* Wpk    = (unsigned short*)(wsb + 393216); // 1 MiB

    prep_kernel    <<<NE / 256,    256, 0, stream>>>(W, wn, Wpk, counts, sumsq);
    vq_mfma_kernel <<<512,         256, 0, stream>>>(z, Wpk, wn, idxbuf, flags);
    rescue_kernel  <<<256,         256, 0, stream>>>(z, W, wn, flags, idxbuf);
    finalize_kernel<<<NROWS / 256, 256, 0, stream>>>(z, W, idxbuf, out_zq, out_idx, counts, sumsq);
    scalars_kernel <<<1,           256, 0, stream>>>(counts, sumsq, out_loss, out_ppl);
}

// Round 9
// 1117.168 us; speedup vs baseline: 2.3482x; 2.3482x over previous
//
#include <hip/hip_runtime.h>
#include <math.h>
#include <float.h>

#define D        64
#define NE       8192
#define NROWS    32768
#define NELEM    (NROWS * D)
#define BETA     0.25f
#define MARGIN   0.75f

#define NTILE    (NE / 16)            // 512 code tiles of 16 codes
#define TPC      16                   // tiles per LDS chunk
#define NCHUNK   (NTILE / TPC)        // 32 chunks
#define CHUNK_US (TPC * 1024)         // ushorts per chunk (16 tiles * 2 KiB)

typedef __attribute__((ext_vector_type(8))) short bf16x8;
typedef __attribute__((ext_vector_type(4))) float f32x4;
typedef __attribute__((ext_vector_type(4))) unsigned int u32x4;

__device__ __forceinline__ unsigned short f2bf(float f) {
    unsigned u = __builtin_bit_cast(unsigned, f);
    unsigned r = (u + 0x7FFFu + ((u >> 16) & 1u)) >> 16;   // round-nearest-even
    return (unsigned short)r;
}
// monotone f32 -> u32 map (ascending floats -> ascending uints), pack with idx
__device__ __forceinline__ unsigned long long packmin(float s, int idx) {
    unsigned u = __builtin_bit_cast(unsigned, s);
    u = (u & 0x80000000u) ? ~u : (u | 0x80000000u);
    return (((unsigned long long)u) << 32) | (unsigned)idx;
}

// ---------------- ws layout (bytes) ----------------
// 0      : wn       (8192 f32)
// 32768  : counts   (8192 f32)
// 65536  : sumsq    (1 double)
// 65552  : nflag    (1 int)
// 66048  : idxbuf   (32768 int)
// 197120 : worklist (32768 int)
// 393216 : Wpk      (packed bf16 of -2W, 1 MiB)

// Kernel A: wn, packed bf16 codebook (-2W), zero accumulators.
// Wpk frag layout: tile t (16 codes), K-half h: ushort idx
// (t*2+h)*512 + (g*16+cl)*8 + j  => lane l reads its 16x16x32 B-fragment
// (col=l&15, k=(l>>4)*8+j) as one contiguous ds_read_b128 at lane*16 B.
__global__ void prep_kernel(const float* __restrict__ W,
                            float* __restrict__ wn,
                            unsigned short* __restrict__ Wpk,
                            float* __restrict__ counts,
                            double* __restrict__ sumsq,
                            int* __restrict__ nflag)
{
    int k = blockIdx.x * 256 + threadIdx.x;  // 0..8191
    const float4* wp = (const float4*)(W + (size_t)k * D);
    float w[64]; float s = 0.f;
#pragma unroll
    for (int j = 0; j < 16; ++j) {
        float4 v = wp[j];
        w[4*j+0]=v.x; w[4*j+1]=v.y; w[4*j+2]=v.z; w[4*j+3]=v.w;
        s += v.x*v.x + v.y*v.y + v.z*v.z + v.w*v.w;
    }
    wn[k] = s;
    counts[k] = 0.f;
    if (k == 0) { *sumsq = 0.0; *nflag = 0; }

    unsigned short hb[64];
#pragma unroll
    for (int d = 0; d < 64; ++d) hb[d] = f2bf(-2.0f * w[d]);

    const int t = k >> 4, cl = k & 15;
#pragma unroll
    for (int h = 0; h < 2; ++h)
#pragma unroll
    for (int g = 0; g < 4; ++g) {
        const unsigned short* src = hb + h*32 + g*8;
        u32x4 pk;
#pragma unroll
        for (int j = 0; j < 4; ++j)
            pk[j] = (unsigned)src[2*j] | ((unsigned)src[2*j+1] << 16);
        *(u32x4*)(Wpk + (size_t)(((t*2 + h)*512) + (g*16 + cl)*8)) = pk;
    }
}

// Kernel B: MFMA argmin, single bf16 hi-pass; flagged rows appended to worklist.
__global__ __launch_bounds__(256, 2) void vq_mfma_kernel(
    const float* __restrict__ z,
    const unsigned short* __restrict__ Wpk,
    const float* __restrict__ wn,
    int* __restrict__ idxbuf,
    int* __restrict__ worklist,
    int* __restrict__ nflag)
{
    __shared__ __align__(16) unsigned short lds[2 * CHUNK_US];  // 64 KiB dbuf

    const int tid  = threadIdx.x;
    const int lane = tid & 63;
    const int wv   = tid >> 6;
    const int strip   = blockIdx.x * 4 + wv;       // 0..2047
    const int rowbase = strip * 16;
    const int cl = lane & 15;                      // A row / D col within tile
    const int kg = lane >> 4;                      // k-group

    bf16x8 a_h[2];
#pragma unroll
    for (int h = 0; h < 2; ++h) {
        const float* zp = z + (size_t)(rowbase + cl) * D + h*32 + kg*8;
        float4 f0 = ((const float4*)zp)[0];
        float4 f1 = ((const float4*)zp)[1];
        float f[8] = {f0.x,f0.y,f0.z,f0.w,f1.x,f1.y,f1.z,f1.w};
        bf16x8 hh;
#pragma unroll
        for (int j = 0; j < 8; ++j) hh[j] = (short)f2bf(f[j]);
        a_h[h] = hh;
    }

    float best[4]  = {FLT_MAX, FLT_MAX, FLT_MAX, FLT_MAX};
    float best2[4] = {FLT_MAX, FLT_MAX, FLT_MAX, FLT_MAX};
    int   besti[4] = {0,0,0,0};

    const u32x4* gsrc = (const u32x4*)Wpk;   // 2048 u32x4 per 32 KiB chunk
    u32x4 stg[8];

#pragma unroll
    for (int i = 0; i < 8; ++i) stg[i] = gsrc[i*256 + tid];
    {
        u32x4* ld = (u32x4*)lds;
#pragma unroll
        for (int i = 0; i < 8; ++i) ld[i*256 + tid] = stg[i];
    }
    __syncthreads();

    int buf = 0;
    for (int c = 0; c < NCHUNK; ++c) {
        if (c + 1 < NCHUNK) {
            const u32x4* gs = gsrc + (size_t)(c+1) * 2048;
#pragma unroll
            for (int i = 0; i < 8; ++i) stg[i] = gs[i*256 + tid];
        }

        float wnv[TPC];
#pragma unroll
        for (int tt = 0; tt < TPC; ++tt)
            wnv[tt] = wn[(c*TPC + tt)*16 + cl];

        const unsigned short* lb = lds + buf * CHUNK_US;
#pragma unroll
        for (int p = 0; p < 8; ++p) {
            const int lt0 = 2*p, lt1 = 2*p + 1;
            const unsigned short* b0p = lb + lt0*1024;
            const unsigned short* b1p = lb + lt1*1024;
            bf16x8 b0h0 = *(const bf16x8*)(b0p +   0 + lane*8);
            bf16x8 b0h1 = *(const bf16x8*)(b0p + 512 + lane*8);
            bf16x8 b1h0 = *(const bf16x8*)(b1p +   0 + lane*8);
            bf16x8 b1h1 = *(const bf16x8*)(b1p + 512 + lane*8);

            f32x4 acc0 = {wnv[lt0], wnv[lt0], wnv[lt0], wnv[lt0]};
            f32x4 acc1 = {wnv[lt1], wnv[lt1], wnv[lt1], wnv[lt1]};
            acc0 = __builtin_amdgcn_mfma_f32_16x16x32_bf16(a_h[0], b0h0, acc0, 0,0,0);
            acc1 = __builtin_amdgcn_mfma_f32_16x16x32_bf16(a_h[0], b1h0, acc1, 0,0,0);
            acc0 = __builtin_amdgcn_mfma_f32_16x16x32_bf16(a_h[1], b0h1, acc0, 0,0,0);
            acc1 = __builtin_amdgcn_mfma_f32_16x16x32_bf16(a_h[1], b1h1, acc1, 0,0,0);

            const int code0 = (c*TPC + lt0)*16 + cl;
            const int code1 = (c*TPC + lt1)*16 + cl;
#pragma unroll
            for (int q = 0; q < 4; ++q) {
                float s0 = acc0[q];
                best2[q] = fminf(best2[q], fmaxf(best[q], s0));
                besti[q] = (s0 < best[q]) ? code0 : besti[q];
                best[q]  = fminf(best[q], s0);
                float s1 = acc1[q];
                best2[q] = fminf(best2[q], fmaxf(best[q], s1));
                besti[q] = (s1 < best[q]) ? code1 : besti[q];
                best[q]  = fminf(best[q], s1);
            }
        }
        __syncthreads();
        if (c + 1 < NCHUNK) {
            u32x4* ld = (u32x4*)(lds + (buf ^ 1) * CHUNK_US);
#pragma unroll
            for (int i = 0; i < 8; ++i) ld[i*256 + tid] = stg[i];
        }
        __syncthreads();
        buf ^= 1;
    }

#pragma unroll
    for (int m = 1; m < 16; m <<= 1) {
#pragma unroll
        for (int q = 0; q < 4; ++q) {
            float ob1 = __shfl_xor(best[q],  m, 64);
            int   oi  = __shfl_xor(besti[q], m, 64);
            float ob2 = __shfl_xor(best2[q], m, 64);
            float nb2 = fminf(fminf(best2[q], ob2), fmaxf(best[q], ob1));
            if (ob1 < best[q]) { best[q] = ob1; besti[q] = oi; }
            best2[q] = nb2;
        }
    }
    if (cl == 0) {
#pragma unroll
        for (int q = 0; q < 4; ++q) {
            int row = rowbase + kg*4 + q;     // C/D: row=(lane>>4)*4+reg [m89]
            idxbuf[row] = besti[q];
            if (best2[q] - best[q] < MARGIN) {
                int pos = atomicAdd(nflag, 1);
                if (pos < NROWS) worklist[pos] = row;
            }
        }
    }
}

// Kernel C: exact fp32 rescue over the compacted worklist.
// Each block-iteration: 8 flagged rows (z staged in LDS, broadcast reads);
// each thread scores 4 codes/sweep x 8 sweeps against all 8 rows.
#define RPB 8
__global__ __launch_bounds__(256) void rescue_kernel(
    const float* __restrict__ z, const float* __restrict__ W,
    const float* __restrict__ wn,
    const int* __restrict__ worklist, const int* __restrict__ nflag,
    int* __restrict__ idxbuf)
{
    const int tid = threadIdx.x;
    const int count = min(*nflag, NROWS);   // defensive clamp (poison guard)
    __shared__ __align__(16) float zr[RPB][64];
    __shared__ unsigned long long red[256];

    for (int base = blockIdx.x * RPB; base < count; base += gridDim.x * RPB) {
        const int nr = min(RPB, count - base);
        __syncthreads();   // protect zr from previous iteration
        if (tid < nr * 16) {
            int r = tid >> 4, jj = tid & 15;
            ((float4*)zr[r])[jj] =
                ((const float4*)(z + (size_t)worklist[base + r] * D))[jj];
        }
        __syncthreads();

        float best[RPB]; int bi[RPB];
#pragma unroll
        for (int r = 0; r < RPB; ++r) { best[r] = FLT_MAX; bi[r] = 0; }

        for (int sw = 0; sw < 8; ++sw) {
            const int cbase = sw * 1024 + tid;   // codes cbase + i*256, i=0..3
            float acc[RPB][4];
#pragma unroll
            for (int r = 0; r < RPB; ++r)
#pragma unroll
                for (int i = 0; i < 4; ++i) acc[r][i] = 0.f;

            const float4* wp0 = (const float4*)(W + (size_t)(cbase        ) * D);
            const float4* wp1 = (const float4*)(W + (size_t)(cbase +  256 ) * D);
            const float4* wp2 = (const float4*)(W + (size_t)(cbase +  512 ) * D);
            const float4* wp3 = (const float4*)(W + (size_t)(cbase +  768 ) * D);
#pragma unroll
            for (int j = 0; j < 16; ++j) {
                float4 w0 = wp0[j], w1 = wp1[j], w2 = wp2[j], w3 = wp3[j];
#pragma unroll
                for (int r = 0; r < RPB; ++r) {
                    float4 zv = ((const float4*)zr[r])[j];  // broadcast b128
                    acc[r][0] += zv.x*w0.x + zv.y*w0.y + zv.z*w0.z + zv.w*w0.w;
                    acc[r][1] += zv.x*w1.x + zv.y*w1.y + zv.z*w1.z + zv.w*w1.w;
                    acc[r][2] += zv.x*w2.x + zv.y*w2.y + zv.z*w2.z + zv.w*w2.w;
                    acc[r][3] += zv.x*w3.x + zv.y*w3.y + zv.z*w3.z + zv.w*w3.w;
                }
            }
            float wn0 = wn[cbase], wn1 = wn[cbase+256],
                  wn2 = wn[cbase+512], wn3 = wn[cbase+768];
#pragma unroll
            for (int r = 0; r < RPB; ++r) {
                float s0 = wn0 - 2.f*acc[r][0];
                float s1 = wn1 - 2.f*acc[r][1];
                float s2 = wn2 - 2.f*acc[r][2];
                float s3 = wn3 - 2.f*acc[r][3];
                if (s0 < best[r]) { best[r] = s0; bi[r] = cbase; }
                if (s1 < best[r]) { best[r] = s1; bi[r] = cbase + 256; }
                if (s2 < best[r]) { best[r] = s2; bi[r] = cbase + 512; }
                if (s3 < best[r]) { best[r] = s3; bi[r] = cbase + 768; }
            }
        }

        // per-row block reduction (nr uniform across block => uniform syncs)
#pragma unroll
        for (int R = 0; R < RPB; ++R) {
            if (R < nr) {
                red[tid] = packmin(best[R], bi[R]);
                __syncthreads();
#pragma unroll
                for (int off = 128; off > 0; off >>= 1) {
                    if (tid < off) {
                        unsigned long long a = red[tid], b = red[tid + off];
                        red[tid] = (b < a) ? b : a;
                    }
                    __syncthreads();
                }
                if (tid == 0)
                    idxbuf[worklist[base + R]] = (int)(red[0] & 0xFFFFFFFFull);
                __syncthreads();
            }
        }
    }
}

// Kernel D: gather z_q, out_idx, counts, sumsq
__global__ void finalize_kernel(const float* __restrict__ z,
                                const float* __restrict__ W,
                                const int* __restrict__ idxbuf,
                                float* __restrict__ out_zq,
                                float* __restrict__ out_idx,
                                float* __restrict__ counts,
                                double* __restrict__ sumsq)
{
    const int n = blockIdx.x * 256 + threadIdx.x;  // 0..32767
    const int bi = idxbuf[n];
    out_idx[n] = (float)bi;
    atomicAdd(&counts[bi], 1.0f);

    const float4* wp = (const float4*)(W + (size_t)bi * D);
    const float4* zp = (const float4*)(z + (size_t)n  * D);
    float4*       op = (float4*)(out_zq + (size_t)n * D);
    float ss = 0.f;
#pragma unroll
    for (int j = 0; j < 16; ++j) {
        float4 wv = wp[j];
        float4 zv = zp[j];
        float dx = wv.x - zv.x, dy = wv.y - zv.y, dz = wv.z - zv.z, dw = wv.w - zv.w;
        ss += dx*dx + dy*dy + dz*dz + dw*dw;
        op[j] = wv;
    }
    __shared__ float red[256];
    red[threadIdx.x] = ss;
    __syncthreads();
#pragma unroll
    for (int off = 128; off > 0; off >>= 1) {
        if (threadIdx.x < off) red[threadIdx.x] += red[threadIdx.x + off];
        __syncthreads();
    }
    if (threadIdx.x == 0) atomicAdd(sumsq, (double)red[0]);
}

// Kernel E: scalars (loss, perplexity)
__global__ void scalars_kernel(const float* __restrict__ counts,
                               const double* __restrict__ sumsq,
                               float* __restrict__ out_loss,
                               float* __restrict__ out_ppl)
{
    __shared__ float red[256];
    float acc = 0.f;
    for (int k = threadIdx.x; k < NE; k += 256) {
        float p = counts[k] * (1.0f / (float)NROWS);
        acc += p * logf(p + 1e-12f);
    }
    red[threadIdx.x] = acc;
    __syncthreads();
#pragma unroll
    for (int off = 128; off > 0; off >>= 1) {
        if (threadIdx.x < off) red[threadIdx.x] += red[threadIdx.x + off];
        __syncthreads();
    }
    if (threadIdx.x == 0) {
        out_ppl[0]  = expf(-red[0]);
        out_loss[0] = (float)(sumsq[0] * ((1.0 + (double)BETA) / (double)NELEM));
    }
}

extern "C" void kernel_launch(void* const* d_in, const int* in_sizes, int n_in,
                              void* d_out, int out_size, void* d_ws, size_t ws_size,
                              hipStream_t stream) {
    const float* z = (const float*)d_in[0];   // [32,1024,64] fp32
    const float* W = (const float*)d_in[1];   // [8192,64]    fp32

    float* out      = (float*)d_out;
    float* out_zq   = out;                     // 2097152
    float* out_loss = out + NELEM;             // 1
    float* out_idx  = out + NELEM + 1;         // 32768 (as float)
    float* out_ppl  = out + NELEM + 1 + NROWS; // 1

    char* wsb = (char*)d_ws;
    float*          wn       = (float*)wsb;                 // 8192 f32
    float*          counts   = (float*)(wsb + 32768);       // 8192 f32
    double*         sumsq    = (double*)(wsb + 65536);      // 1 f64
    int*            nflag    = (int*)(wsb + 65552);         // 1 int
    int*            idxbuf   = (int*)(wsb + 66048);         // 32768 int
    int*            worklist = (int*)(wsb + 197120);        // 32768 int
    unsigned short* Wpk      = (unsigned short*)(wsb + 393216); // 1 MiB

    prep_kernel    <<<NE / 256,    256, 0, stream>>>(W, wn, Wpk, counts, sumsq, nflag);
    vq_mfma_kernel <<<512,         256, 0, stream>>>(z, Wpk, wn, idxbuf, worklist, nflag);
    rescue_kernel  <<<512,         256, 0, stream>>>(z, W, wn, worklist, nflag, idxbuf);
    finalize_kernel<<<NROWS / 256, 256, 0, stream>>>(z, W, idxbuf, out_zq, out_idx, counts, sumsq);
    scalars_kernel <<<1,           256, 0, stream>>>(counts, sumsq, out_loss, out_ppl);
}

// Round 11
// 325.868 us; speedup vs baseline: 8.0501x; 3.4283x over previous
//
#include <hip/hip_runtime.h>
#include <math.h>
#include <float.h>

#define D        64
#define NE       8192
#define NROWS    32768
#define NELEM    (NROWS * D)
#define BETA     0.25f
#define MARGIN   0.4f

#define NTILE    (NE / 16)            // 512 code tiles of 16 codes
#define TPC      16                   // tiles per LDS chunk
#define NCHUNK   (NTILE / TPC)        // 32 chunks
#define CHUNK_US (TPC * 1024)         // ushorts per chunk (16 tiles * 2 KiB)

typedef __attribute__((ext_vector_type(8))) short bf16x8;
typedef __attribute__((ext_vector_type(4))) float f32x4;
typedef __attribute__((ext_vector_type(4))) unsigned int u32x4;

__device__ __forceinline__ unsigned short f2bf(float f) {
    unsigned u = __builtin_bit_cast(unsigned, f);
    unsigned r = (u + 0x7FFFu + ((u >> 16) & 1u)) >> 16;   // round-nearest-even
    return (unsigned short)r;
}
// monotone f32 -> u32 map (ascending floats -> ascending uints), pack with idx
__device__ __forceinline__ unsigned long long packmin(float s, int idx) {
    unsigned u = __builtin_bit_cast(unsigned, s);
    u = (u & 0x80000000u) ? ~u : (u | 0x80000000u);
    return (((unsigned long long)u) << 32) | (unsigned)idx;
}

// ---------------- ws layout (bytes) ----------------
// 0      : wn       (8192 f32)
// 32768  : counts   (8192 f32)
// 65536  : sumsq    (1 double)
// 65552  : nflag    (1 int)
// 66048  : idxbuf   (32768 int)
// 197120 : worklist (32768 int)
// 393216 : Wpk      (packed bf16 of -2W, 1 MiB)

// Kernel A: wn, packed bf16 codebook (-2W), zero accumulators.
// Wpk frag layout: tile t (16 codes), K-half h: ushort idx
// (t*2+h)*512 + (g*16+cl)*8 + j  => lane l reads its 16x16x32 B-fragment
// (col=l&15, k=(l>>4)*8+j) as one contiguous ds_read_b128 at lane*16 B.
__global__ void prep_kernel(const float* __restrict__ W,
                            float* __restrict__ wn,
                            unsigned short* __restrict__ Wpk,
                            float* __restrict__ counts,
                            double* __restrict__ sumsq,
                            int* __restrict__ nflag)
{
    int k = blockIdx.x * 256 + threadIdx.x;  // 0..8191
    const float4* wp = (const float4*)(W + (size_t)k * D);
    float w[64]; float s = 0.f;
#pragma unroll
    for (int j = 0; j < 16; ++j) {
        float4 v = wp[j];
        w[4*j+0]=v.x; w[4*j+1]=v.y; w[4*j+2]=v.z; w[4*j+3]=v.w;
        s += v.x*v.x + v.y*v.y + v.z*v.z + v.w*v.w;
    }
    wn[k] = s;
    counts[k] = 0.f;
    if (k == 0) { *sumsq = 0.0; *nflag = 0; }

    unsigned short hb[64];
#pragma unroll
    for (int d = 0; d < 64; ++d) hb[d] = f2bf(-2.0f * w[d]);

    const int t = k >> 4, cl = k & 15;
#pragma unroll
    for (int h = 0; h < 2; ++h)
#pragma unroll
    for (int g = 0; g < 4; ++g) {
        const unsigned short* src = hb + h*32 + g*8;
        u32x4 pk;
#pragma unroll
        for (int j = 0; j < 4; ++j)
            pk[j] = (unsigned)src[2*j] | ((unsigned)src[2*j+1] << 16);
        *(u32x4*)(Wpk + (size_t)(((t*2 + h)*512) + (g*16 + cl)*8)) = pk;
    }
}

// Kernel B: MFMA argmin, single bf16 hi-pass; flagged rows appended to worklist.
__global__ __launch_bounds__(256, 2) void vq_mfma_kernel(
    const float* __restrict__ z,
    const unsigned short* __restrict__ Wpk,
    const float* __restrict__ wn,
    int* __restrict__ idxbuf,
    int* __restrict__ worklist,
    int* __restrict__ nflag)
{
    __shared__ __align__(16) unsigned short lds[2 * CHUNK_US];  // 64 KiB dbuf

    const int tid  = threadIdx.x;
    const int lane = tid & 63;
    const int wv   = tid >> 6;
    const int strip   = blockIdx.x * 4 + wv;       // 0..2047
    const int rowbase = strip * 16;
    const int cl = lane & 15;                      // A row / D col within tile
    const int kg = lane >> 4;                      // k-group

    bf16x8 a_h[2];
#pragma unroll
    for (int h = 0; h < 2; ++h) {
        const float* zp = z + (size_t)(rowbase + cl) * D + h*32 + kg*8;
        float4 f0 = ((const float4*)zp)[0];
        float4 f1 = ((const float4*)zp)[1];
        float f[8] = {f0.x,f0.y,f0.z,f0.w,f1.x,f1.y,f1.z,f1.w};
        bf16x8 hh;
#pragma unroll
        for (int j = 0; j < 8; ++j) hh[j] = (short)f2bf(f[j]);
        a_h[h] = hh;
    }

    float best[4]  = {FLT_MAX, FLT_MAX, FLT_MAX, FLT_MAX};
    float best2[4] = {FLT_MAX, FLT_MAX, FLT_MAX, FLT_MAX};
    int   besti[4] = {0,0,0,0};

    const u32x4* gsrc = (const u32x4*)Wpk;   // 2048 u32x4 per 32 KiB chunk
    u32x4 stg[8];

#pragma unroll
    for (int i = 0; i < 8; ++i) stg[i] = gsrc[i*256 + tid];
    {
        u32x4* ld = (u32x4*)lds;
#pragma unroll
        for (int i = 0; i < 8; ++i) ld[i*256 + tid] = stg[i];
    }
    __syncthreads();

    int buf = 0;
    for (int c = 0; c < NCHUNK; ++c) {
        if (c + 1 < NCHUNK) {
            const u32x4* gs = gsrc + (size_t)(c+1) * 2048;
#pragma unroll
            for (int i = 0; i < 8; ++i) stg[i] = gs[i*256 + tid];
        }

        float wnv[TPC];
#pragma unroll
        for (int tt = 0; tt < TPC; ++tt)
            wnv[tt] = wn[(c*TPC + tt)*16 + cl];

        const unsigned short* lb = lds + buf * CHUNK_US;
#pragma unroll
        for (int p = 0; p < 8; ++p) {
            const int lt0 = 2*p, lt1 = 2*p + 1;
            const unsigned short* b0p = lb + lt0*1024;
            const unsigned short* b1p = lb + lt1*1024;
            bf16x8 b0h0 = *(const bf16x8*)(b0p +   0 + lane*8);
            bf16x8 b0h1 = *(const bf16x8*)(b0p + 512 + lane*8);
            bf16x8 b1h0 = *(const bf16x8*)(b1p +   0 + lane*8);
            bf16x8 b1h1 = *(const bf16x8*)(b1p + 512 + lane*8);

            f32x4 acc0 = {wnv[lt0], wnv[lt0], wnv[lt0], wnv[lt0]};
            f32x4 acc1 = {wnv[lt1], wnv[lt1], wnv[lt1], wnv[lt1]};
            acc0 = __builtin_amdgcn_mfma_f32_16x16x32_bf16(a_h[0], b0h0, acc0, 0,0,0);
            acc1 = __builtin_amdgcn_mfma_f32_16x16x32_bf16(a_h[0], b1h0, acc1, 0,0,0);
            acc0 = __builtin_amdgcn_mfma_f32_16x16x32_bf16(a_h[1], b0h1, acc0, 0,0,0);
            acc1 = __builtin_amdgcn_mfma_f32_16x16x32_bf16(a_h[1], b1h1, acc1, 0,0,0);

            const int code0 = (c*TPC + lt0)*16 + cl;
            const int code1 = (c*TPC + lt1)*16 + cl;
#pragma unroll
            for (int q = 0; q < 4; ++q) {
                float s0 = acc0[q];
                best2[q] = fminf(best2[q], fmaxf(best[q], s0));
                besti[q] = (s0 < best[q]) ? code0 : besti[q];
                best[q]  = fminf(best[q], s0);
                float s1 = acc1[q];
                best2[q] = fminf(best2[q], fmaxf(best[q], s1));
                besti[q] = (s1 < best[q]) ? code1 : besti[q];
                best[q]  = fminf(best[q], s1);
            }
        }
        __syncthreads();
        if (c + 1 < NCHUNK) {
            u32x4* ld = (u32x4*)(lds + (buf ^ 1) * CHUNK_US);
#pragma unroll
            for (int i = 0; i < 8; ++i) ld[i*256 + tid] = stg[i];
        }
        __syncthreads();
        buf ^= 1;
    }

#pragma unroll
    for (int m = 1; m < 16; m <<= 1) {
#pragma unroll
        for (int q = 0; q < 4; ++q) {
            float ob1 = __shfl_xor(best[q],  m, 64);
            int   oi  = __shfl_xor(besti[q], m, 64);
            float ob2 = __shfl_xor(best2[q], m, 64);
            float nb2 = fminf(fminf(best2[q], ob2), fmaxf(best[q], ob1));
            if (ob1 < best[q]) { best[q] = ob1; besti[q] = oi; }
            best2[q] = nb2;
        }
    }
    if (cl == 0) {
#pragma unroll
        for (int q = 0; q < 4; ++q) {
            int row = rowbase + kg*4 + q;     // C/D: row=(lane>>4)*4+reg [m89]
            idxbuf[row] = besti[q];
            if (best2[q] - best[q] < MARGIN) {
                int pos = atomicAdd(nflag, 1);
                if (pos < NROWS) worklist[pos] = row;
            }
        }
    }
}

// Kernel C: exact fp32 rescue over the compacted worklist.
// Per block-iteration: 8 flagged rows (z in LDS, broadcast reads); each
// thread scores 2 codes/sweep x 16 sweeps vs all 8 rows (acc[8][2] = 16 VGPR;
// #pragma unroll 4 limits W-load hoisting; launch_bounds caps VGPR at 128 —
// round-9 profile showed VGPR=256 + 403 MB scratch writes from spills).
#define RPB 8
__global__ __launch_bounds__(256, 4) void rescue_kernel(
    const float* __restrict__ z, const float* __restrict__ W,
    const float* __restrict__ wn,
    const int* __restrict__ worklist, const int* __restrict__ nflag,
    int* __restrict__ idxbuf)
{
    const int tid  = threadIdx.x;
    const int lane = tid & 63;
    const int wid  = tid >> 6;
    const int count = min(*nflag, NROWS);   // defensive clamp (poison guard)
    __shared__ __align__(16) float zr[RPB][64];
    __shared__ unsigned long long wred[4][RPB];

    for (int base = blockIdx.x * RPB; base < count; base += gridDim.x * RPB) {
        const int nr = min(RPB, count - base);
        __syncthreads();   // protect zr/wred from previous iteration
        if (tid < nr * 16) {
            int r = tid >> 4, jj = tid & 15;
            ((float4*)zr[r])[jj] =
                ((const float4*)(z + (size_t)worklist[base + r] * D))[jj];
        }
        __syncthreads();

        float best[RPB]; int bi[RPB];
#pragma unroll
        for (int r = 0; r < RPB; ++r) { best[r] = FLT_MAX; bi[r] = 0; }

        for (int sw = 0; sw < 16; ++sw) {
            const int c0 = sw * 512 + tid;       // thread's codes: c0, c0+256
            float acc[RPB][2];
#pragma unroll
            for (int r = 0; r < RPB; ++r) { acc[r][0] = 0.f; acc[r][1] = 0.f; }

            const float4* wp0 = (const float4*)(W + (size_t)c0 * D);
            const float4* wp1 = (const float4*)(W + (size_t)(c0 + 256) * D);
#pragma unroll 4
            for (int j = 0; j < 16; ++j) {
                float4 w0 = wp0[j], w1 = wp1[j];
#pragma unroll
                for (int r = 0; r < RPB; ++r) {
                    float4 zv = ((const float4*)zr[r])[j];  // LDS broadcast
                    acc[r][0] += zv.x*w0.x + zv.y*w0.y + zv.z*w0.z + zv.w*w0.w;
                    acc[r][1] += zv.x*w1.x + zv.y*w1.y + zv.z*w1.z + zv.w*w1.w;
                }
            }
            float wn0 = wn[c0], wn1 = wn[c0 + 256];
#pragma unroll
            for (int r = 0; r < RPB; ++r) {
                float s0 = wn0 - 2.f*acc[r][0];
                float s1 = wn1 - 2.f*acc[r][1];
                if (s0 < best[r]) { best[r] = s0; bi[r] = c0; }
                if (s1 < best[r]) { best[r] = s1; bi[r] = c0 + 256; }
            }
        }

        // per-wave shuffle reduction (no barriers), then 4-way LDS merge
#pragma unroll
        for (int r = 0; r < RPB; ++r) {
            unsigned long long v = packmin(best[r], bi[r]);
#pragma unroll
            for (int m = 1; m < 64; m <<= 1) {
                unsigned long long o = __shfl_xor(v, m, 64);
                v = (o < v) ? o : v;
            }
            if (lane == 0) wred[wid][r] = v;
        }
        __syncthreads();
        if (tid < nr) {
            unsigned long long v = wred[0][tid];
#pragma unroll
            for (int w2 = 1; w2 < 4; ++w2) {
                unsigned long long o = wred[w2][tid];
                v = (o < v) ? o : v;
            }
            idxbuf[worklist[base + tid]] = (int)(v & 0xFFFFFFFFull);
        }
    }
}

// Kernel D: gather z_q, out_idx, counts, sumsq
__global__ void finalize_kernel(const float* __restrict__ z,
                                const float* __restrict__ W,
                                const int* __restrict__ idxbuf,
                                float* __restrict__ out_zq,
                                float* __restrict__ out_idx,
                                float* __restrict__ counts,
                                double* __restrict__ sumsq)
{
    const int n = blockIdx.x * 256 + threadIdx.x;  // 0..32767
    const int bi = idxbuf[n];
    out_idx[n] = (float)bi;
    atomicAdd(&counts[bi], 1.0f);

    const float4* wp = (const float4*)(W + (size_t)bi * D);
    const float4* zp = (const float4*)(z + (size_t)n  * D);
    float4*       op = (float4*)(out_zq + (size_t)n * D);
    float ss = 0.f;
#pragma unroll
    for (int j = 0; j < 16; ++j) {
        float4 wv = wp[j];
        float4 zv = zp[j];
        float dx = wv.x - zv.x, dy = wv.y - zv.y, dz = wv.z - zv.z, dw = wv.w - zv.w;
        ss += dx*dx + dy*dy + dz*dz + dw*dw;
        op[j] = wv;
    }
    __shared__ float red[256];
    red[threadIdx.x] = ss;
    __syncthreads();
#pragma unroll
    for (int off = 128; off > 0; off >>= 1) {
        if (threadIdx.x < off) red[threadIdx.x] += red[threadIdx.x + off];
        __syncthreads();
    }
    if (threadIdx.x == 0) atomicAdd(sumsq, (double)red[0]);
}

// Kernel E: scalars (loss, perplexity)
__global__ void scalars_kernel(const float* __restrict__ counts,
                               const double* __restrict__ sumsq,
                               float* __restrict__ out_loss,
                               float* __restrict__ out_ppl)
{
    __shared__ float red[256];
    float acc = 0.f;
    for (int k = threadIdx.x; k < NE; k += 256) {
        float p = counts[k] * (1.0f / (float)NROWS);
        acc += p * logf(p + 1e-12f);
    }
    red[threadIdx.x] = acc;
    __syncthreads();
#pragma unroll
    for (int off = 128; off > 0; off >>= 1) {
        if (threadIdx.x < off) red[threadIdx.x] += red[threadIdx.x + off];
        __syncthreads();
    }
    if (threadIdx.x == 0) {
        out_ppl[0]  = expf(-red[0]);
        out_loss[0] = (float)(sumsq[0] * ((1.0 + (double)BETA) / (double)NELEM));
    }
}

extern "C" void kernel_launch(void* const* d_in, const int* in_sizes, int n_in,
                              void* d_out, int out_size, void* d_ws, size_t ws_size,
                              hipStream_t stream) {
    const float* z = (const float*)d_in[0];   // [32,1024,64] fp32
    const float* W = (const float*)d_in[1];   // [8192,64]    fp32

    float* out      = (float*)d_out;
    float* out_zq   = out;                     // 2097152
    float* out_loss = out + NELEM;             // 1
    float* out_idx  = out + NELEM + 1;         // 32768 (as float)
    float* out_ppl  = out + NELEM + 1 + NROWS; // 1

    char* wsb = (char*)d_ws;
    float*          wn       = (float*)wsb;                 // 8192 f32
    float*          counts   = (float*)(wsb + 32768);       // 8192 f32
    double*         sumsq    = (double*)(wsb + 65536);      // 1 f64
    int*            nflag    = (int*)(wsb + 65552);         // 1 int
    int*            idxbuf   = (int*)(wsb + 66048);         // 32768 int
    int*            worklist = (int*)(wsb + 197120);        // 32768 int
    unsigned short* Wpk      = (unsigned short*)(wsb + 393216); // 1 MiB

    prep_kernel    <<<NE / 256,    256, 0, stream>>>(W, wn, Wpk, counts, sumsq, nflag);
    vq_mfma_kernel <<<512,         256, 0, stream>>>(z, Wpk, wn, idxbuf, worklist, nflag);
    rescue_kernel  <<<512,         256, 0, stream>>>(z, W, wn, worklist, nflag, idxbuf);
    finalize_kernel<<<NROWS / 256, 256, 0, stream>>>(z, W, idxbuf, out_zq, out_idx, counts, sumsq);
    scalars_kernel <<<1,           256, 0, stream>>>(counts, sumsq, out_loss, out_ppl);
}